// Round 6
// baseline (474.301 us; speedup 1.0000x reference)
//
#include <hip/hip_runtime.h>

// RNN: B=256, T=512, I=256, H=128, O=1000, fp32 in/out.
// Internals fp16 (RTZ). xp stored as fp16 (32 MiB in ws).
// FUSED producer/consumer, round 6: grid = EXACTLY 256 blocks (1 per CU at
// 40KB LDS) to kill the CU contention that poisoned round 5 (1040 blocks ->
// 4/CU -> rnn blocks shared their CU with 3 producers -> step time ~2x).
//   blocks 0..15  : recurrence consumers (8 waves, unchanged chain).
//   blocks 16..255: 240 persistent producers, 4-5 tiles each, stage-major.
// Sync: per-(stage, batch-group) counters ctr[4][16]; producer bumps its
// group after __threadfence; consumer b spins (acquire, AGENT) on
// ctr[s][b]==16 then __threadfence. Proven-correct protocol from round 5.
// No deadlock: consumers never hold resources producers need (1 block/CU).

#define HID    128
#define TSTEPS 512
#define BATCH  256
#define INDIM  256
#define ODIM   1000

typedef _Float16 f16x8 __attribute__((ext_vector_type(8)));
typedef __fp16   fp16x2 __attribute__((ext_vector_type(2)));
typedef float    f32x4 __attribute__((ext_vector_type(4)));

__device__ __forceinline__ unsigned pk16(float a, float b) {
    union { fp16x2 h; unsigned u; } t;
    t.h = __builtin_amdgcn_cvt_pkrtz(a, b);   // packs 2 fp32 -> 2 fp16 (RTZ)
    return t.u;
}
__device__ __forceinline__ float tanh_fast(float v) {
    float e = __expf(2.f * v);
    float r = __builtin_amdgcn_rcpf(e + 1.f);
    return __builtin_fmaf(-2.f, r, 1.f);
}

#define CTR_OFF (33u << 20)   // byte offset of int ctr[64] inside ws

// ---------------- k_zero: reset stage counters ------------------------------
__global__ void k_zero(float* ws) {
    int* ctr = (int*)((char*)ws + CTR_OFF);
    if (threadIdx.x < 64) ctr[threadIdx.x] = 0;
}

// ---------------- fused kernel ----------------------------------------------
// Producer tile tau in [0,1024), stage-major: stage = tau>>8, bq = tau&255.
// Tile = batch row bq, t in [stage*128, stage*128+128) -> xp rows
// m0 = (bq*4+stage)*128 .. +128 (row index = batch*512 + t).

__global__ __launch_bounds__(512) void k_fused(const float* __restrict__ x,
                                               const float* __restrict__ Wih,
                                               const float* __restrict__ bih,
                                               const float* __restrict__ bhh,
                                               const float* __restrict__ Whh,
                                               float* __restrict__ ws) {
    __shared__ __align__(16) _Float16 xs[2][4096];
    __shared__ __align__(16) _Float16 wsm[2][4096];
    __shared__ __align__(16) _Float16 hp[2][16 * 128];

    const int tid  = threadIdx.x;
    const int wave = tid >> 6, lane = tid & 63;
    const int quad = lane >> 4, l16 = lane & 15;
    int* ctr = (int*)((char*)ws + CTR_OFF);
    _Float16* xp16 = (_Float16*)ws;

    if (blockIdx.x >= 16) {
        // ================= producer role (240 blocks, 4-5 tiles each) =======
        const int pb = blockIdx.x - 16;
        const int wm = wave >> 1, wn = wave & 1;   // wm 0..3 (32 rows), wn 0..1

        // staging geometry (tile-independent): li = q*512+tid -> row, col
        int srow[2], scol[2], sdst[2];
#pragma unroll
        for (int q = 0; q < 2; q++) {
            int li = q * 512 + tid;
            srow[q] = li >> 3;
            scol[q] = li & 7;
            sdst[q] = srow[q] * 32 + ((((scol[q] >> 1) ^ srow[q]) & 3) << 3) + ((scol[q] & 1) << 2);
        }

        f32x4 bias_v[4];
#pragma unroll
        for (int nt = 0; nt < 4; nt++) {
            int j0 = wn * 64 + nt * 16 + quad * 4;
            bias_v[nt] = *(const f32x4*)(bih + j0) + *(const f32x4*)(bhh + j0);
        }

        float4 rx[2], rw[2];
#define LOAD_STAGE(KC)                                                              \
        {                                                                           \
            _Pragma("unroll") for (int q = 0; q < 2; q++) {                         \
                rx[q] = *(const float4*)(x + (size_t)(m0 + srow[q]) * INDIM + (KC) * 32 + scol[q] * 4); \
                rw[q] = *(const float4*)(Wih + (size_t)srow[q] * INDIM + (KC) * 32 + scol[q] * 4);      \
            }                                                                       \
        }
#define WRITE_STAGE(BUF)                                                            \
        {                                                                           \
            _Pragma("unroll") for (int q = 0; q < 2; q++) {                         \
                uint2 px, pw;                                                       \
                px.x = pk16(rx[q].x, rx[q].y); px.y = pk16(rx[q].z, rx[q].w);       \
                pw.x = pk16(rw[q].x, rw[q].y); pw.y = pk16(rw[q].z, rw[q].w);       \
                *(uint2*)&xs[BUF][sdst[q]]  = px;                                   \
                *(uint2*)&wsm[BUF][sdst[q]] = pw;                                   \
            }                                                                       \
        }

        for (int tau = pb; tau < 1024; tau += 240) {
            const int stage = tau >> 8;
            const int bq    = tau & 255;
            const int m0    = (bq * 4 + stage) * 128;

            f32x4 acc[2][4];
#pragma unroll
            for (int mt = 0; mt < 2; mt++)
#pragma unroll
                for (int nt = 0; nt < 4; nt++) {
                    acc[mt][nt].x = 0.f; acc[mt][nt].y = 0.f;
                    acc[mt][nt].z = 0.f; acc[mt][nt].w = 0.f;
                }

            LOAD_STAGE(0);
            WRITE_STAGE(0);
            __syncthreads();

            for (int kc = 0; kc < 8; kc++) {
                const int b = kc & 1;
                if (kc < 7) LOAD_STAGE(kc + 1);

                f16x8 a[2], bw[4];
#pragma unroll
                for (int mt = 0; mt < 2; mt++) {
                    int row = wm * 32 + mt * 16 + l16;
                    a[mt] = *(const f16x8*)&xs[b][row * 32 + (((quad ^ row) & 3) << 3)];
                }
#pragma unroll
                for (int nt = 0; nt < 4; nt++) {
                    int row = wn * 64 + nt * 16 + l16;
                    bw[nt] = *(const f16x8*)&wsm[b][row * 32 + (((quad ^ row) & 3) << 3)];
                }
                // swapped: A = W (i->j), B = x (cols = xp-rows)
#pragma unroll
                for (int mt = 0; mt < 2; mt++)
#pragma unroll
                    for (int nt = 0; nt < 4; nt++)
                        acc[mt][nt] = __builtin_amdgcn_mfma_f32_16x16x32_f16(bw[nt], a[mt], acc[mt][nt], 0, 0, 0);

                if (kc < 7) WRITE_STAGE(b ^ 1);
                __syncthreads();
            }

            // D: col(l16) = xp-row, row(quad*4+reg) = j. Store fp16 uint2 (4 j).
#pragma unroll
            for (int mt = 0; mt < 2; mt++) {
                int row = m0 + wm * 32 + mt * 16 + l16;
#pragma unroll
                for (int nt = 0; nt < 4; nt++) {
                    int col = wn * 64 + nt * 16 + quad * 4;
                    f32x4 v = acc[mt][nt] + bias_v[nt];
                    uint2 p;
                    p.x = pk16(v.x, v.y); p.y = pk16(v.z, v.w);
                    *(uint2*)&xp16[(size_t)row * HID + col] = p;
                }
            }

            // publish this tile: stores done -> fence -> bump (stage, group)
            __syncthreads();
            if (tid == 0) {
                __threadfence();
                atomicAdd(&ctr[stage * 16 + (bq >> 4)], 1);
            }
        }
#undef LOAD_STAGE
#undef WRITE_STAGE
        return;
    }

    // ================= recurrence consumer role (blocks 0..15) ==============
    const int r0 = blockIdx.x * 16;

    // A-frags: W[j=16w+l16][k = kc*32 + quad*8 + i]  (load before any spin)
    f16x8 Wf[4];
#pragma unroll
    for (int kc = 0; kc < 4; kc++) {
        const float* p = Whh + (size_t)(16 * wave + l16) * HID + kc * 32 + quad * 8;
        float4 e0 = *(const float4*)p, e1 = *(const float4*)(p + 4);
        union { unsigned u[4]; f16x8 v; } t;
        t.u[0] = pk16(e0.x, e0.y); t.u[1] = pk16(e0.z, e0.w);
        t.u[2] = pk16(e1.x, e1.y); t.u[3] = pk16(e1.z, e1.w);
        Wf[kc] = t.v;
    }

    const int raddr0 = l16 * 128 + ((((0 * 4 + quad) ^ l16) & 15) << 3);
    const int raddr1 = l16 * 128 + ((((1 * 4 + quad) ^ l16) & 15) << 3);
    const int raddr2 = l16 * 128 + ((((2 * 4 + quad) ^ l16) & 15) << 3);
    const int raddr3 = l16 * 128 + ((((3 * 4 + quad) ^ l16) & 15) << 3);
    const int waddr  = l16 * 128 + ((((2 * wave + (quad >> 1)) ^ l16) & 15) << 3) + ((quad & 1) << 2);

    const _Float16* xpb = xp16 + (size_t)(r0 + l16) * (TSTEPS * HID) + 16 * wave + 4 * quad;

    // consumer b only needs its own batch group: ctr[s*16 + b] == 16
#define WAITSTAGE(S)                                                                \
    {                                                                               \
        if (tid == 0) {                                                             \
            long iv = 0;                                                            \
            while (__hip_atomic_load(&ctr[(S) * 16 + blockIdx.x], __ATOMIC_ACQUIRE, \
                                     __HIP_MEMORY_SCOPE_AGENT) < 16 &&              \
                   ++iv < 200000000L) {}                                            \
        }                                                                           \
        __syncthreads();                                                            \
        __threadfence();                                                            \
    }

#define CVT4(DST, SRC)                                                              \
    {                                                                               \
        union { uint2 u; _Float16 h[4]; } cv_; cv_.u = (SRC);                       \
        DST.x = (float)cv_.h[0]; DST.y = (float)cv_.h[1];                           \
        DST.z = (float)cv_.h[2]; DST.w = (float)cv_.h[3];                           \
    }

#define RNN_STEP4(TV, XQI, XQC, PB) {                                             \
    uint2 pw;                                                                     \
    pw.x = pk16(tanh_fast(C.x), tanh_fast(C.y));                                  \
    pw.y = pk16(tanh_fast(C.z), tanh_fast(C.w));                                  \
    *(uint2*)&hp[PB][waddr] = pw;                                                 \
    if ((TV) + 4 < TSTEPS)                                                        \
        XQI = *(const uint2*)(xpb + (size_t)((TV) + 4) * HID);                    \
    asm volatile("s_waitcnt lgkmcnt(0)\n\ts_barrier" ::: "memory");               \
    f32x4 ch; CVT4(ch, XQC);                /* overlaps ds_read latency */        \
    f16x8 H0 = *(const f16x8*)&hp[PB][raddr0];                                    \
    f16x8 H1 = *(const f16x8*)&hp[PB][raddr1];                                    \
    f16x8 H2 = *(const f16x8*)&hp[PB][raddr2];                                    \
    f16x8 H3 = *(const f16x8*)&hp[PB][raddr3];                                    \
    f32x4 cl;                                                                     \
    cl.x = 0.f; cl.y = 0.f; cl.z = 0.f; cl.w = 0.f;                               \
    ch = __builtin_amdgcn_mfma_f32_16x16x32_f16(Wf[0], H0, ch, 0, 0, 0);          \
    cl = __builtin_amdgcn_mfma_f32_16x16x32_f16(Wf[2], H2, cl, 0, 0, 0);          \
    ch = __builtin_amdgcn_mfma_f32_16x16x32_f16(Wf[1], H1, ch, 0, 0, 0);          \
    cl = __builtin_amdgcn_mfma_f32_16x16x32_f16(Wf[3], H3, cl, 0, 0, 0);          \
    C = ch + cl;                                                                  \
}

    WAITSTAGE(0);

    // C init = xp_0; prefetch xp_1..3 (raw fp16x4)
    f32x4 C;
    uint2 xq0, xq1, xq2, xq3;
    {
        uint2 c0 = *(const uint2*)(xpb);
        CVT4(C, c0);
    }
    xq1 = *(const uint2*)(xpb + 1 * HID);
    xq2 = *(const uint2*)(xpb + 2 * HID);
    xq3 = *(const uint2*)(xpb + 3 * HID);

    for (int t = 0; t < 124; t += 4) {
        RNN_STEP4(t,     xq0, xq1, 0);
        RNN_STEP4(t + 1, xq1, xq2, 1);
        RNN_STEP4(t + 2, xq2, xq3, 0);
        RNN_STEP4(t + 3, xq3, xq0, 1);
    }
    WAITSTAGE(1);
    for (int t = 124; t < 252; t += 4) {
        RNN_STEP4(t,     xq0, xq1, 0);
        RNN_STEP4(t + 1, xq1, xq2, 1);
        RNN_STEP4(t + 2, xq2, xq3, 0);
        RNN_STEP4(t + 3, xq3, xq0, 1);
    }
    WAITSTAGE(2);
    for (int t = 252; t < 380; t += 4) {
        RNN_STEP4(t,     xq0, xq1, 0);
        RNN_STEP4(t + 1, xq1, xq2, 1);
        RNN_STEP4(t + 2, xq2, xq3, 0);
        RNN_STEP4(t + 3, xq3, xq0, 1);
    }
    WAITSTAGE(3);
    for (int t = 380; t < 508; t += 4) {
        RNN_STEP4(t,     xq0, xq1, 0);
        RNN_STEP4(t + 1, xq1, xq2, 1);
        RNN_STEP4(t + 2, xq2, xq3, 0);
        RNN_STEP4(t + 3, xq3, xq0, 1);
    }
    RNN_STEP4(508, xq0, xq1, 0);
    RNN_STEP4(509, xq1, xq2, 1);
    RNN_STEP4(510, xq2, xq3, 0);

    // h_511 -> stash fp16 over xp[row][0][:] (own rows, consumed long ago)
    {
        uint2 p;
        p.x = pk16(tanh_fast(C.x), tanh_fast(C.y));
        p.y = pk16(tanh_fast(C.z), tanh_fast(C.w));
        *(uint2*)(xp16 + (size_t)(r0 + l16) * (TSTEPS * HID) + 16 * wave + 4 * quad) = p;
    }
#undef RNN_STEP4
#undef CVT4
#undef WAITSTAGE
}

// ---------------- k_fc: out = h_last @ W_fc^T + b_fc ------------------------
__global__ __launch_bounds__(256) void k_fc(const float* __restrict__ ws,
                                            const float* __restrict__ Wfc,
                                            const float* __restrict__ bfc,
                                            float* __restrict__ out) {
    __shared__ float hb[HID];
    const int b   = blockIdx.x;
    const int tid = threadIdx.x;
    const _Float16* xp16 = (const _Float16*)ws;
    if (tid < HID) hb[tid] = (float)xp16[(size_t)b * (TSTEPS * HID) + tid];
    __syncthreads();

    for (int o = tid; o < ODIM; o += 256) {
        const float* wr = Wfc + (size_t)o * HID;
        float acc = 0.f;
#pragma unroll
        for (int q = 0; q < 32; q++) {
            float4 wv = *(const float4*)(wr + q * 4);
            float4 hv = *(const float4*)&hb[q * 4];
            acc += wv.x * hv.x + wv.y * hv.y + wv.z * hv.z + wv.w * hv.w;
        }
        out[(size_t)b * ODIM + o] = acc + bfc[o];
    }
}

extern "C" void kernel_launch(void* const* d_in, const int* in_sizes, int n_in,
                              void* d_out, int out_size, void* d_ws, size_t ws_size,
                              hipStream_t stream) {
    const float* x   = (const float*)d_in[0];
    const float* Wih = (const float*)d_in[1];
    const float* Whh = (const float*)d_in[2];
    const float* bih = (const float*)d_in[3];
    const float* bhh = (const float*)d_in[4];
    const float* Wfc = (const float*)d_in[5];
    const float* bfc = (const float*)d_in[6];
    float* out = (float*)d_out;
    float* ws  = (float*)d_ws;   // xp16 32MiB + ctr[64] at +33MiB

    k_zero <<<dim3(1),    dim3(64),  0, stream>>>(ws);
    k_fused<<<dim3(256),  dim3(512), 0, stream>>>(x, Wih, bih, bhh, Whh, ws);
    k_fc   <<<dim3(BATCH), dim3(256), 0, stream>>>(ws, Wfc, bfc, out);
}

// Round 7
// 438.072 us; speedup vs baseline: 1.0827x; 1.0827x over previous
//
#include <hip/hip_runtime.h>

// RNN: B=256, T=512, I=256, H=128, O=1000, fp32 in/out.
// Internals fp16 (RTZ). xp stored fp16 (32 MiB in ws) -- validated in rounds
// 5/6 (absmax unchanged 0.0078125). Split kernels (fusion abandoned: R5
// contention / R6 producer starvation). Structure = round 4 (375.4us best)
// with fp16 xp as the single change: phase1 write traffic halves.
// ws: xp16[131072][128] fp16 = 32 MiB. h_last[r] overwrites xp16[r*512+0][:]
// after the recurrence (each block's own rows, consumed at t=0 long before).

#define HID    128
#define TSTEPS 512
#define BATCH  256
#define INDIM  256
#define ODIM   1000

typedef _Float16 f16x8 __attribute__((ext_vector_type(8)));
typedef __fp16   fp16x2 __attribute__((ext_vector_type(2)));
typedef float    f32x4 __attribute__((ext_vector_type(4)));

__device__ __forceinline__ unsigned pk16(float a, float b) {
    union { fp16x2 h; unsigned u; } t;
    t.h = __builtin_amdgcn_cvt_pkrtz(a, b);   // packs 2 fp32 -> 2 fp16 (RTZ)
    return t.u;
}
// tanh without clamp: exp2 overflow->inf->rcp->0 gives +1; underflow->0 gives -1.
__device__ __forceinline__ float tanh_fast(float v) {
    float e = __expf(2.f * v);                 // v_mul + v_exp_f32
    float r = __builtin_amdgcn_rcpf(e + 1.f);  // v_add + v_rcp_f32
    return __builtin_fmaf(-2.f, r, 1.f);
}

// ---------------- Kernel 1: xp = x @ W_ih^T + (b_ih + b_hh), fp16 out -------
// MFMA 16x16x32 f16, double-buffered LDS staging, fp16 conversion at stage
// time. Swapped epilogue (R4-proven): D col(l16)=x-row m, row(quad*4+reg)=j
// -> lane holds 4 consecutive j at fixed m: store = uint2 (4 fp16) per tile.
__global__ __launch_bounds__(256) void k_phase1(const float* __restrict__ x,
                                                const float* __restrict__ Wih,
                                                const float* __restrict__ bih,
                                                const float* __restrict__ bhh,
                                                float* __restrict__ ws) {
    __shared__ __align__(16) _Float16 xs[2][4096];   // x tile fp16
    __shared__ __align__(16) _Float16 wsm[2][4096];  // W tile fp16

    const int tid  = threadIdx.x;
    const int wave = tid >> 6, lane = tid & 63;
    const int quad = lane >> 4, l16 = lane & 15;
    const int wm = wave >> 1, wn = wave & 1;
    const int m0 = blockIdx.x * 128;
    _Float16* xp16 = (_Float16*)ws;

    // staging geometry: li = q*256+tid -> row = li>>3 (0..127), c = li&7 (4-float units)
    int srow[4], scol[4], sdst[4];
#pragma unroll
    for (int q = 0; q < 4; q++) {
        int li = q * 256 + tid;
        srow[q] = li >> 3;
        scol[q] = li & 7;
        sdst[q] = srow[q] * 32 + ((((scol[q] >> 1) ^ srow[q]) & 3) << 3) + ((scol[q] & 1) << 2);
    }

    // bias for this lane's 4 consecutive j: j0 = wn*64 + nt*16 + quad*4
    f32x4 bias_v[4];
#pragma unroll
    for (int nt = 0; nt < 4; nt++) {
        int j0 = wn * 64 + nt * 16 + quad * 4;
        bias_v[nt] = *(const f32x4*)(bih + j0) + *(const f32x4*)(bhh + j0);
    }

    float4 rx[4], rw[4];
#define LOAD_STAGE(KC)                                                              \
    {                                                                               \
        _Pragma("unroll") for (int q = 0; q < 4; q++) {                             \
            rx[q] = *(const float4*)(x + (size_t)(m0 + srow[q]) * INDIM + (KC) * 32 + scol[q] * 4); \
            rw[q] = *(const float4*)(Wih + (size_t)srow[q] * INDIM + (KC) * 32 + scol[q] * 4);      \
        }                                                                           \
    }
#define WRITE_STAGE(BUF)                                                            \
    {                                                                               \
        _Pragma("unroll") for (int q = 0; q < 4; q++) {                             \
            uint2 px, pw;                                                           \
            px.x = pk16(rx[q].x, rx[q].y); px.y = pk16(rx[q].z, rx[q].w);           \
            pw.x = pk16(rw[q].x, rw[q].y); pw.y = pk16(rw[q].z, rw[q].w);           \
            *(uint2*)&xs[BUF][sdst[q]]  = px;                                       \
            *(uint2*)&wsm[BUF][sdst[q]] = pw;                                       \
        }                                                                           \
    }

    f32x4 acc[4][4];
#pragma unroll
    for (int mt = 0; mt < 4; mt++)
#pragma unroll
        for (int nt = 0; nt < 4; nt++) {
            acc[mt][nt].x = 0.f; acc[mt][nt].y = 0.f;
            acc[mt][nt].z = 0.f; acc[mt][nt].w = 0.f;
        }

    LOAD_STAGE(0);
    WRITE_STAGE(0);
    __syncthreads();

    for (int kc = 0; kc < 8; kc++) {
        const int b = kc & 1;
        if (kc < 7) LOAD_STAGE(kc + 1);

        f16x8 a[4], bw[4];
#pragma unroll
        for (int mt = 0; mt < 4; mt++) {
            int row = wm * 64 + mt * 16 + l16;
            a[mt] = *(const f16x8*)&xs[b][row * 32 + (((quad ^ row) & 3) << 3)];
        }
#pragma unroll
        for (int nt = 0; nt < 4; nt++) {
            int row = wn * 64 + nt * 16 + l16;
            bw[nt] = *(const f16x8*)&wsm[b][row * 32 + (((quad ^ row) & 3) << 3)];
        }
        // swapped: A-operand = W (i=j), B-operand = x (j-col = m)
#pragma unroll
        for (int mt = 0; mt < 4; mt++)
#pragma unroll
            for (int nt = 0; nt < 4; nt++)
                acc[mt][nt] = __builtin_amdgcn_mfma_f32_16x16x32_f16(bw[nt], a[mt], acc[mt][nt], 0, 0, 0);

        if (kc < 7) WRITE_STAGE(b ^ 1);
        __syncthreads();
    }

    // Swapped C layout: col(l16) = x-row m, row(quad*4+reg) = j.
    // Lane stores 4 consecutive j (fp16) at its row -> one uint2 per (mt,nt).
#pragma unroll
    for (int mt = 0; mt < 4; mt++) {
        int row = m0 + wm * 64 + mt * 16 + l16;
#pragma unroll
        for (int nt = 0; nt < 4; nt++) {
            int col = wn * 64 + nt * 16 + quad * 4;
            f32x4 v = acc[mt][nt] + bias_v[nt];
            uint2 p;
            p.x = pk16(v.x, v.y); p.y = pk16(v.z, v.w);
            *(uint2*)&xp16[(size_t)row * HID + col] = p;
        }
    }
#undef LOAD_STAGE
#undef WRITE_STAGE
}

// ---------------- Kernel 2: recurrence (MFMA f16, 8 waves, swapped) ---------
// 16 blocks x 512 thr. Block b: rows [16b,16b+16). Wave w: j in [16w,16w+16).
// D[j][m] = sum_k W[j][k] h[m][k]. A = W_hh persistent VGPRs; B = h in LDS
// (proven conflict-free b128 XOR-chunk reads). C layout col(l16)=m,
// row(quad*4+reg)=j: h-write = 1 ds_write_b64; xp load = 1 dwordx2 (fp16x4);
// cvt overlapped with ds_read latency. 2 planes, 1 raw barrier per step.
#define CVT4(DST, SRC)                                                              \
    {                                                                               \
        union { uint2 u; _Float16 h[4]; } cv_; cv_.u = (SRC);                       \
        DST.x = (float)cv_.h[0]; DST.y = (float)cv_.h[1];                           \
        DST.z = (float)cv_.h[2]; DST.w = (float)cv_.h[3];                           \
    }

#define RNN_STEP4(TV, XQI, XQC, PB) {                                             \
    uint2 pw;                                                                     \
    pw.x = pk16(tanh_fast(C.x), tanh_fast(C.y));                                  \
    pw.y = pk16(tanh_fast(C.z), tanh_fast(C.w));                                  \
    *(uint2*)&hp[PB][waddr] = pw;                                                 \
    if ((TV) + 4 < TSTEPS)                                                        \
        XQI = *(const uint2*)(xpb + (size_t)((TV) + 4) * HID);                    \
    asm volatile("s_waitcnt lgkmcnt(0)\n\ts_barrier" ::: "memory");               \
    f32x4 ch; CVT4(ch, XQC);                /* overlaps ds_read latency */        \
    f16x8 H0 = *(const f16x8*)&hp[PB][raddr0];                                    \
    f16x8 H1 = *(const f16x8*)&hp[PB][raddr1];                                    \
    f16x8 H2 = *(const f16x8*)&hp[PB][raddr2];                                    \
    f16x8 H3 = *(const f16x8*)&hp[PB][raddr3];                                    \
    f32x4 cl;                                                                     \
    cl.x = 0.f; cl.y = 0.f; cl.z = 0.f; cl.w = 0.f;                               \
    ch = __builtin_amdgcn_mfma_f32_16x16x32_f16(Wf[0], H0, ch, 0, 0, 0);          \
    cl = __builtin_amdgcn_mfma_f32_16x16x32_f16(Wf[2], H2, cl, 0, 0, 0);          \
    ch = __builtin_amdgcn_mfma_f32_16x16x32_f16(Wf[1], H1, ch, 0, 0, 0);          \
    cl = __builtin_amdgcn_mfma_f32_16x16x32_f16(Wf[3], H3, cl, 0, 0, 0);          \
    C = ch + cl;                                                                  \
}

__global__ __launch_bounds__(512) void k_rnn4(const float* __restrict__ Whh,
                                              float* __restrict__ ws) {
    __shared__ __align__(16) _Float16 hp[2][16 * 128];
    const int tid  = threadIdx.x;
    const int wave = tid >> 6, lane = tid & 63;
    const int quad = lane >> 4, l16 = lane & 15;
    const int r0   = blockIdx.x * 16;
    _Float16* xp16 = (_Float16*)ws;

    // A-frags: W[j=16w+l16][k = kc*32 + quad*8 + i]
    f16x8 Wf[4];
#pragma unroll
    for (int kc = 0; kc < 4; kc++) {
        const float* p = Whh + (size_t)(16 * wave + l16) * HID + kc * 32 + quad * 8;
        float4 e0 = *(const float4*)p, e1 = *(const float4*)(p + 4);
        union { unsigned u[4]; f16x8 v; } t;
        t.u[0] = pk16(e0.x, e0.y); t.u[1] = pk16(e0.z, e0.w);
        t.u[2] = pk16(e1.x, e1.y); t.u[3] = pk16(e1.z, e1.w);
        Wf[kc] = t.v;
    }

    // LDS addrs (fp16-elem units). h row m = l16 (256B = 16 chunks of 16B),
    // chunk XOR-swizzled with l16. Reads: full chunk (kc*4+quad)^l16.
    // Write: lane's j-quad (j=16w+4q..+3) = 8B at chunk 2w+(q>>1), half (q&1).
    const int raddr0 = l16 * 128 + ((((0 * 4 + quad) ^ l16) & 15) << 3);
    const int raddr1 = l16 * 128 + ((((1 * 4 + quad) ^ l16) & 15) << 3);
    const int raddr2 = l16 * 128 + ((((2 * 4 + quad) ^ l16) & 15) << 3);
    const int raddr3 = l16 * 128 + ((((3 * 4 + quad) ^ l16) & 15) << 3);
    const int waddr  = l16 * 128 + ((((2 * wave + (quad >> 1)) ^ l16) & 15) << 3) + ((quad & 1) << 2);

    // xp base for this lane: batch row r0+l16, j-base = 16*wave + 4*quad
    const _Float16* xpb = xp16 + (size_t)(r0 + l16) * (TSTEPS * HID) + 16 * wave + 4 * quad;

    // C init = xp_0 (h_{-1}=0); prefetch xp_1..3 (uint2 = fp16x4 each)
    f32x4 C;
    uint2 xq0, xq1, xq2, xq3;
    {
        uint2 c0 = *(const uint2*)(xpb);
        CVT4(C, c0);
    }
    xq1 = *(const uint2*)(xpb + 1 * HID);
    xq2 = *(const uint2*)(xpb + 2 * HID);
    xq3 = *(const uint2*)(xpb + 3 * HID);

    for (int t = 0; t < 508; t += 4) {
        RNN_STEP4(t,     xq0, xq1, 0);
        RNN_STEP4(t + 1, xq1, xq2, 1);
        RNN_STEP4(t + 2, xq2, xq3, 0);
        RNN_STEP4(t + 3, xq3, xq0, 1);
    }
    RNN_STEP4(508, xq0, xq1, 0);
    RNN_STEP4(509, xq1, xq2, 1);
    RNN_STEP4(510, xq2, xq3, 0);

    // h_511 -> stash fp16 over xp[row][0][:] (own rows, consumed long ago)
    {
        uint2 p;
        p.x = pk16(tanh_fast(C.x), tanh_fast(C.y));
        p.y = pk16(tanh_fast(C.z), tanh_fast(C.w));
        *(uint2*)(xp16 + (size_t)(r0 + l16) * (TSTEPS * HID) + 16 * wave + 4 * quad) = p;
    }
}
#undef RNN_STEP4
#undef CVT4

// ---------------- Kernel 3: out = h_last @ W_fc^T + b_fc --------------------
__global__ __launch_bounds__(256) void k_fc(const float* __restrict__ ws,
                                            const float* __restrict__ Wfc,
                                            const float* __restrict__ bfc,
                                            float* __restrict__ out) {
    __shared__ float hb[HID];
    const int b   = blockIdx.x;
    const int tid = threadIdx.x;
    const _Float16* xp16 = (const _Float16*)ws;
    if (tid < HID) hb[tid] = (float)xp16[(size_t)b * (TSTEPS * HID) + tid];
    __syncthreads();

    for (int o = tid; o < ODIM; o += 256) {
        const float* wr = Wfc + (size_t)o * HID;
        float acc = 0.f;
#pragma unroll
        for (int q = 0; q < 32; q++) {
            float4 wv = *(const float4*)(wr + q * 4);
            float4 hv = *(const float4*)&hb[q * 4];
            acc += wv.x * hv.x + wv.y * hv.y + wv.z * hv.z + wv.w * hv.w;
        }
        out[(size_t)b * ODIM + o] = acc + bfc[o];
    }
}

extern "C" void kernel_launch(void* const* d_in, const int* in_sizes, int n_in,
                              void* d_out, int out_size, void* d_ws, size_t ws_size,
                              hipStream_t stream) {
    const float* x   = (const float*)d_in[0];
    const float* Wih = (const float*)d_in[1];
    const float* Whh = (const float*)d_in[2];
    const float* bih = (const float*)d_in[3];
    const float* bhh = (const float*)d_in[4];
    const float* Wfc = (const float*)d_in[5];
    const float* bfc = (const float*)d_in[6];
    float* out = (float*)d_out;
    float* ws  = (float*)d_ws;  // xp16 = 32 MiB

    k_phase1<<<dim3(1024), dim3(256), 0, stream>>>(x, Wih, bih, bhh, ws);
    k_rnn4  <<<dim3(16),   dim3(512), 0, stream>>>(Whh, ws);
    k_fc    <<<dim3(BATCH), dim3(256), 0, stream>>>(ws, Wfc, bfc, out);
}

// Round 8
// 370.911 us; speedup vs baseline: 1.2787x; 1.1811x over previous
//
#include <hip/hip_runtime.h>

// RNN: B=256, T=512, I=256, H=128, O=1000, fp32 in/out.
// Internals fp16 (RTZ); xp stored fp32 (64 MiB) -- the R7 fp16-xp experiment
// SLOWED k_rnn4 47% (8B-load/CVT path on the serial chain); reverted.
// This round's single change vs R4 (375.4us best): phase1 staging prefetch
// depth 2 for x (two register sets), W depth 1 (L2-hot). Everything else is
// R4 verbatim. ws: xp[131072][128] fp32 = 64 MiB; h_last[r] overwrites
// xp[r*512+0][:] after the recurrence (own rows, consumed at t=0 long before).

#define HID    128
#define TSTEPS 512
#define BATCH  256
#define INDIM  256
#define ODIM   1000

typedef _Float16 f16x8 __attribute__((ext_vector_type(8)));
typedef __fp16   fp16x2 __attribute__((ext_vector_type(2)));
typedef float    f32x4 __attribute__((ext_vector_type(4)));

__device__ __forceinline__ unsigned pk16(float a, float b) {
    union { fp16x2 h; unsigned u; } t;
    t.h = __builtin_amdgcn_cvt_pkrtz(a, b);   // packs 2 fp32 -> 2 fp16 (RTZ)
    return t.u;
}
// tanh without clamp: exp2 overflow->inf->rcp->0 gives +1; underflow->0 gives -1.
__device__ __forceinline__ float tanh_fast(float v) {
    float e = __expf(2.f * v);                 // v_mul + v_exp_f32
    float r = __builtin_amdgcn_rcpf(e + 1.f);  // v_add + v_rcp_f32
    return __builtin_fmaf(-2.f, r, 1.f);
}

// ---------------- Kernel 1: xp = x @ W_ih^T + (b_ih + b_hh) ----------------
// MFMA 16x16x32 f16, double-buffered LDS, fp16 conversion at stage time.
// NEW: x-loads double-prefetched (rxA/rxB, ~2 kc-iters = ~1200cy slack vs
// ~900cy HBM latency); W single-prefetched (L2-hot, ~220cy). Swapped epilogue
// (R4-proven): D col(l16)=x-row m, row(quad*4+reg)=j -> dwordx4 stores.
__global__ __launch_bounds__(256) void k_phase1(const float* __restrict__ x,
                                                const float* __restrict__ Wih,
                                                const float* __restrict__ bih,
                                                const float* __restrict__ bhh,
                                                float* __restrict__ xp) {
    __shared__ __align__(16) _Float16 xs[2][4096];   // x tile fp16
    __shared__ __align__(16) _Float16 wsm[2][4096];  // W tile fp16

    const int tid  = threadIdx.x;
    const int wave = tid >> 6, lane = tid & 63;
    const int quad = lane >> 4, l16 = lane & 15;
    const int wm = wave >> 1, wn = wave & 1;
    const int m0 = blockIdx.x * 128;

    // staging geometry: li = q*256+tid -> row = li>>3 (0..127), c = li&7 (4-float units)
    int srow[4], scol[4], sdst[4];
#pragma unroll
    for (int q = 0; q < 4; q++) {
        int li = q * 256 + tid;
        srow[q] = li >> 3;
        scol[q] = li & 7;
        sdst[q] = srow[q] * 32 + ((((scol[q] >> 1) ^ srow[q]) & 3) << 3) + ((scol[q] & 1) << 2);
    }

    // bias for this lane's 4 consecutive j: j0 = wn*64 + nt*16 + quad*4
    f32x4 bias_v[4];
#pragma unroll
    for (int nt = 0; nt < 4; nt++) {
        int j0 = wn * 64 + nt * 16 + quad * 4;
        bias_v[nt] = *(const f32x4*)(bih + j0) + *(const f32x4*)(bhh + j0);
    }

    float4 rxA[4], rxB[4], rwA[4];
#define LOADX(SET, KC)                                                              \
    {                                                                               \
        _Pragma("unroll") for (int q = 0; q < 4; q++)                               \
            SET[q] = *(const float4*)(x + (size_t)(m0 + srow[q]) * INDIM + (KC) * 32 + scol[q] * 4); \
    }
#define LOADW(KC)                                                                   \
    {                                                                               \
        _Pragma("unroll") for (int q = 0; q < 4; q++)                               \
            rwA[q] = *(const float4*)(Wih + (size_t)srow[q] * INDIM + (KC) * 32 + scol[q] * 4);      \
    }
#define WRITE_STAGE(BUF, XS)                                                        \
    {                                                                               \
        _Pragma("unroll") for (int q = 0; q < 4; q++) {                             \
            uint2 px, pw;                                                           \
            px.x = pk16(XS[q].x, XS[q].y); px.y = pk16(XS[q].z, XS[q].w);           \
            pw.x = pk16(rwA[q].x, rwA[q].y); pw.y = pk16(rwA[q].z, rwA[q].w);       \
            *(uint2*)&xs[BUF][sdst[q]]  = px;                                       \
            *(uint2*)&wsm[BUF][sdst[q]] = pw;                                       \
        }                                                                           \
    }

    f32x4 acc[4][4];
#pragma unroll
    for (int mt = 0; mt < 4; mt++)
#pragma unroll
        for (int nt = 0; nt < 4; nt++) {
            acc[mt][nt].x = 0.f; acc[mt][nt].y = 0.f;
            acc[mt][nt].z = 0.f; acc[mt][nt].w = 0.f;
        }

    // prologue: stage kc0; prefetch x1 (A), x2 (B), W1
    LOADX(rxA, 0); LOADW(0);
    WRITE_STAGE(0, rxA);
    LOADX(rxA, 1); LOADW(1);
    LOADX(rxB, 2);
    __syncthreads();

    // x(n) lives in rxA when n odd, rxB when n even (n>=1).
#pragma unroll
    for (int kc = 0; kc < 8; kc++) {
        const int b = kc & 1;

        f16x8 a[4], bw[4];
#pragma unroll
        for (int mt = 0; mt < 4; mt++) {
            int row = wm * 64 + mt * 16 + l16;
            a[mt] = *(const f16x8*)&xs[b][row * 32 + (((quad ^ row) & 3) << 3)];
        }
#pragma unroll
        for (int nt = 0; nt < 4; nt++) {
            int row = wn * 64 + nt * 16 + l16;
            bw[nt] = *(const f16x8*)&wsm[b][row * 32 + (((quad ^ row) & 3) << 3)];
        }
        // swapped: A-operand = W (i=j), B-operand = x (j-col = m)
#pragma unroll
        for (int mt = 0; mt < 4; mt++)
#pragma unroll
            for (int nt = 0; nt < 4; nt++)
                acc[mt][nt] = __builtin_amdgcn_mfma_f32_16x16x32_f16(bw[nt], a[mt], acc[mt][nt], 0, 0, 0);

        if (kc < 7) {
            // consume x(kc+1) from its set + W(kc+1) from rwA
            if (kc & 1) { WRITE_STAGE(b ^ 1, rxB); } else { WRITE_STAGE(b ^ 1, rxA); }
            // refill: W(kc+2) depth-1; x(kc+3) into the just-freed set
            if (kc + 2 < 8) LOADW(kc + 2);
            if (kc + 3 < 8) {
                if (kc & 1) { LOADX(rxB, kc + 3); } else { LOADX(rxA, kc + 3); }
            }
        }
        __syncthreads();
    }

    // Swapped C layout: col(l16) = x-row m, row(quad*4+reg) = j.
    // Lane stores 4 consecutive j at its row -> one dwordx4 per (mt,nt).
#pragma unroll
    for (int mt = 0; mt < 4; mt++) {
        int row = m0 + wm * 64 + mt * 16 + l16;
#pragma unroll
        for (int nt = 0; nt < 4; nt++) {
            int col = wn * 64 + nt * 16 + quad * 4;
            *(f32x4*)&xp[(size_t)row * HID + col] = acc[mt][nt] + bias_v[nt];
        }
    }
#undef LOADX
#undef LOADW
#undef WRITE_STAGE
}

// ---------------- Kernel 2: recurrence (MFMA f16, 8 waves, swapped) ---------
// R4 VERBATIM (142.7us proven). 16 blocks x 512 thr. Block b: rows [16b,16b+16).
// Wave w: j in [16w,16w+16). D[j][m] = sum_k W[j][k] h[m][k]. A = W_hh
// persistent VGPRs; B = h in LDS (conflict-free b128 XOR-chunk reads).
// C layout col(l16)=m, row(quad*4+reg)=j: h-write = 1 ds_write_b64; xp load =
// 1 dwordx4 fp32. 2 planes, 1 raw barrier per step.
#define RNN_STEP4(TV, XQI, XQC, PB) {                                             \
    uint2 pw;                                                                     \
    pw.x = pk16(tanh_fast(C.x), tanh_fast(C.y));                                  \
    pw.y = pk16(tanh_fast(C.z), tanh_fast(C.w));                                  \
    *(uint2*)&hp[PB][waddr] = pw;                                                 \
    if ((TV) + 4 < TSTEPS)                                                        \
        XQI = *(const f32x4*)(xpb + (size_t)((TV) + 4) * HID);                    \
    asm volatile("s_waitcnt lgkmcnt(0)\n\ts_barrier" ::: "memory");               \
    f16x8 H0 = *(const f16x8*)&hp[PB][raddr0];                                    \
    f16x8 H1 = *(const f16x8*)&hp[PB][raddr1];                                    \
    f16x8 H2 = *(const f16x8*)&hp[PB][raddr2];                                    \
    f16x8 H3 = *(const f16x8*)&hp[PB][raddr3];                                    \
    f32x4 ch = XQC, cl;                                                           \
    cl.x = 0.f; cl.y = 0.f; cl.z = 0.f; cl.w = 0.f;                               \
    ch = __builtin_amdgcn_mfma_f32_16x16x32_f16(Wf[0], H0, ch, 0, 0, 0);          \
    cl = __builtin_amdgcn_mfma_f32_16x16x32_f16(Wf[2], H2, cl, 0, 0, 0);          \
    ch = __builtin_amdgcn_mfma_f32_16x16x32_f16(Wf[1], H1, ch, 0, 0, 0);          \
    cl = __builtin_amdgcn_mfma_f32_16x16x32_f16(Wf[3], H3, cl, 0, 0, 0);          \
    C = ch + cl;                                                                  \
}

__global__ __launch_bounds__(512) void k_rnn4(const float* __restrict__ Whh,
                                              float* __restrict__ ws) {
    __shared__ __align__(16) _Float16 hp[2][16 * 128];
    const int tid  = threadIdx.x;
    const int wave = tid >> 6, lane = tid & 63;
    const int quad = lane >> 4, l16 = lane & 15;
    const int r0   = blockIdx.x * 16;

    // A-frags: W[j=16w+l16][k = kc*32 + quad*8 + i]
    f16x8 Wf[4];
#pragma unroll
    for (int kc = 0; kc < 4; kc++) {
        const float* p = Whh + (size_t)(16 * wave + l16) * HID + kc * 32 + quad * 8;
        float4 e0 = *(const float4*)p, e1 = *(const float4*)(p + 4);
        union { unsigned u[4]; f16x8 v; } t;
        t.u[0] = pk16(e0.x, e0.y); t.u[1] = pk16(e0.z, e0.w);
        t.u[2] = pk16(e1.x, e1.y); t.u[3] = pk16(e1.z, e1.w);
        Wf[kc] = t.v;
    }

    // LDS addrs (fp16-elem units). h row m = l16 (256B = 16 chunks of 16B),
    // chunk XOR-swizzled with l16. Reads: full chunk (kc*4+quad)^l16.
    // Write: lane's j-quad (j=16w+4q..+3) = 8B at chunk 2w+(q>>1), half (q&1).
    const int raddr0 = l16 * 128 + ((((0 * 4 + quad) ^ l16) & 15) << 3);
    const int raddr1 = l16 * 128 + ((((1 * 4 + quad) ^ l16) & 15) << 3);
    const int raddr2 = l16 * 128 + ((((2 * 4 + quad) ^ l16) & 15) << 3);
    const int raddr3 = l16 * 128 + ((((3 * 4 + quad) ^ l16) & 15) << 3);
    const int waddr  = l16 * 128 + ((((2 * wave + (quad >> 1)) ^ l16) & 15) << 3) + ((quad & 1) << 2);

    // xp base for this lane: batch row r0+l16, j-base = 16*wave + 4*quad
    const float* xpb = ws + (size_t)(r0 + l16) * (TSTEPS * HID) + 16 * wave + 4 * quad;

    // C init = xp_0 (h_{-1}=0); prefetch xp_1..3 (one dwordx4 each)
    f32x4 C, xq0, xq1, xq2, xq3;
    C   = *(const f32x4*)(xpb);
    xq1 = *(const f32x4*)(xpb + 1 * HID);
    xq2 = *(const f32x4*)(xpb + 2 * HID);
    xq3 = *(const f32x4*)(xpb + 3 * HID);

    for (int t = 0; t < 508; t += 4) {
        RNN_STEP4(t,     xq0, xq1, 0);
        RNN_STEP4(t + 1, xq1, xq2, 1);
        RNN_STEP4(t + 2, xq2, xq3, 0);
        RNN_STEP4(t + 3, xq3, xq0, 1);
    }
    RNN_STEP4(508, xq0, xq1, 0);
    RNN_STEP4(509, xq1, xq2, 1);
    RNN_STEP4(510, xq2, xq3, 0);

    // h_511 -> stash fp32 over xp[row][0][:] (own rows, consumed long ago)
    f32x4 o;
    o.x = tanh_fast(C.x); o.y = tanh_fast(C.y);
    o.z = tanh_fast(C.z); o.w = tanh_fast(C.w);
    *(f32x4*)(ws + (size_t)(r0 + l16) * (TSTEPS * HID) + 16 * wave + 4 * quad) = o;
}
#undef RNN_STEP4

// ---------------- Kernel 3: out = h_last @ W_fc^T + b_fc --------------------
__global__ __launch_bounds__(256) void k_fc(const float* __restrict__ ws,
                                            const float* __restrict__ Wfc,
                                            const float* __restrict__ bfc,
                                            float* __restrict__ out) {
    __shared__ float hb[HID];
    const int b   = blockIdx.x;
    const int tid = threadIdx.x;
    if (tid < HID) hb[tid] = ws[(size_t)b * (TSTEPS * HID) + tid];
    __syncthreads();

    for (int o = tid; o < ODIM; o += 256) {
        const float* wr = Wfc + (size_t)o * HID;
        float acc = 0.f;
#pragma unroll
        for (int q = 0; q < 32; q++) {
            float4 wv = *(const float4*)(wr + q * 4);
            float4 hv = *(const float4*)&hb[q * 4];
            acc += wv.x * hv.x + wv.y * hv.y + wv.z * hv.z + wv.w * hv.w;
        }
        out[(size_t)b * ODIM + o] = acc + bfc[o];
    }
}

extern "C" void kernel_launch(void* const* d_in, const int* in_sizes, int n_in,
                              void* d_out, int out_size, void* d_ws, size_t ws_size,
                              hipStream_t stream) {
    const float* x   = (const float*)d_in[0];
    const float* Wih = (const float*)d_in[1];
    const float* Whh = (const float*)d_in[2];
    const float* bih = (const float*)d_in[3];
    const float* bhh = (const float*)d_in[4];
    const float* Wfc = (const float*)d_in[5];
    const float* bfc = (const float*)d_in[6];
    float* out = (float*)d_out;
    float* ws  = (float*)d_ws;  // 64 MiB fp32 xp

    k_phase1<<<dim3(1024), dim3(256), 0, stream>>>(x, Wih, bih, bhh, ws);
    k_rnn4  <<<dim3(16),   dim3(512), 0, stream>>>(Whh, ws);
    k_fc    <<<dim3(BATCH), dim3(256), 0, stream>>>(ws, Wfc, bfc, out);
}